// Round 10
// baseline (121.913 us; speedup 1.0000x reference)
//
#include <hip/hip_runtime.h>
#include <math.h>

#define CIN    16
#define COUT   64
#define H      256
#define W      256
#define OH     254
#define OW     254
#define NTAP   9
#define RING   4

typedef _Float16 f16x8  __attribute__((ext_vector_type(8)));
typedef float    f32x16 __attribute__((ext_vector_type(16)));

// Bank-spreading bijective slot map: [px 256][g 2] -> slot in 512-entry row region.
#define XS(px, g) ((((px) << 1) | (g)) ^ (((px) >> 2) & 7))

// weight pack: [tap 9][msub 2][lane 64][e 8] fp16; co=(l&31)+32m, cin=8*(l>>5)+e
__global__ void wpack_kernel(const float* __restrict__ w, _Float16* __restrict__ wpk) {
    int idx = blockIdx.x * 256 + threadIdx.x;   // 0..9215
    if (idx >= NTAP * 2 * 64 * 8) return;
    int e = idx & 7, l = (idx >> 3) & 63, m = (idx >> 9) & 1, t = idx >> 10;
    int co  = (l & 31) + 32 * m;
    int cin = 8 * (l >> 5) + e;
    wpk[idx] = (_Float16)w[((co * CIN + cin) * 3 + t / 3) * 3 + (t % 3)];
}

__device__ __forceinline__ float tanh_fast(float v) {
    float e = __expf(2.0f * v);
    return 1.0f - 2.0f * __builtin_amdgcn_rcpf(e + 1.0f);
}
__device__ __forceinline__ float min3f(float a, float b, float c) {
    return fminf(fminf(a, b), c);   // clang fuses to v_min3_f32
}

// 256 thr = 4 waves; block = one {21,22}-row x 256-px strip; 3 blocks/CU.
// Register diet: m=0 weight frags in VGPR (36), m=1 frags re-read from LDS
// (9 ds_read/row), bias via wave-uniform SGPR loads + cndmask (no cbias regs).
__global__ __launch_bounds__(256, 3) void conv_mfma_kernel(
        const float* __restrict__ x, const f16x8* __restrict__ wpk,
        const float* __restrict__ bias, float* __restrict__ out) {
    __shared__ f16x8 xs[RING * 512];   // 32 KiB: 4-row ring
    __shared__ f16x8 wl[NTAP * 64];    // 9 KiB: m=1 weight frags

    const int tid  = threadIdx.x;
    const int lane = tid & 63;

    int bid = blockIdx.x;
    int nb  = (bid & 7) * 96 + (bid >> 3);      // 768 = 8*96, bijective XCD swizzle
    int b   = nb / 12;                          // image
    int s   = nb - 12 * b;                      // strip 0..11
    const int h  = (s < 2) ? 22 : 21;           // output rows this strip
    const int r0 = (s < 2) ? 22 * s : 44 + 21 * (s - 2);

    const float* xb = x + (size_t)b * CIN * H * W;

    // ---- weights: m=0 -> 36 VGPRs; m=1 -> LDS (FIX: strided loop, all 576) ----
    f16x8 wreg[NTAP];
#pragma unroll
    for (int t = 0; t < NTAP; ++t) wreg[t] = wpk[(t * 2) * 64 + lane];
    for (int i = tid; i < NTAP * 64; i += 256)
        wl[i] = wpk[((i >> 6) * 2 + 1) * 64 + (i & 63)];

    const int g   = tid >> 7;                   // staging cin half
    const int w2  = (tid & 127) * 2;            // staging pixel pair
    const int wv  = tid >> 6;
    const int l31 = lane & 31;
    const int g2  = lane >> 5;
    const int P   = wv * 64;                    // wave pixel base

    float2 vv[8];

#define SLOAD(rowAbs)                                                           \
    {                                                                           \
        int r_ = (rowAbs) > 255 ? 255 : (rowAbs);                               \
        const float* p_ = xb + (size_t)r_ * W + w2;                             \
        _Pragma("unroll")                                                       \
        for (int c = 0; c < 8; ++c)                                             \
            vv[c] = *(const float2*)(p_ + (size_t)(8 * g + c) * (H * W));       \
    }
#define SWRITE(slot)                                                            \
    {                                                                           \
        f16x8 q0, q1;                                                           \
        _Pragma("unroll")                                                       \
        for (int c = 0; c < 8; ++c) { q0[c] = (_Float16)vv[c].x;                \
                                      q1[c] = (_Float16)vv[c].y; }              \
        xs[(slot) * 512 + XS(w2,     g)] = q0;                                  \
        xs[(slot) * 512 + XS(w2 + 1, g)] = q1;                                  \
    }

    // ---- prologue: input rows r0..r0+2 -> slots 0..2 ----
#pragma unroll
    for (int i = 0; i < 3; ++i) { SLOAD(r0 + i) SWRITE(i) }
    __syncthreads();

    // fragment slot offsets (loop-invariant)
    int off[3][2];
#pragma unroll
    for (int kw = 0; kw < 3; ++kw)
#pragma unroll
        for (int n = 0; n < 2; ++n) {
            int px = P + 32 * n + l31 + kw;
            if (px > 255) px = 255;
            off[kw][n] = XS(px, g2);
        }

#pragma unroll 1
    for (int r = 0; r < h; ++r) {
        // issue-early: global loads for input row r+3 (consumed after MFMAs)
        const bool doStage = (r + 3 <= h + 1);
        if (doStage) SLOAD(r0 + r + 3)

        // bias as transient C fragments: wave-uniform scalar loads + g2-select
        f32x16 cb0, cb1;
#pragma unroll
        for (int q = 0; q < 16; ++q) {
            const int i0 = (q & 3) + 8 * (q >> 2);
            cb0[q] = g2 ? bias[i0 + 4]  : bias[i0];
            cb1[q] = g2 ? bias[i0 + 36] : bias[i0 + 32];
        }

        const f16x8* xr0 = xs + ((r    ) & 3) * 512;
        const f16x8* xr1 = xs + ((r + 1) & 3) * 512;
        const f16x8* xr2 = xs + ((r + 2) & 3) * 512;

        f32x16 acc[2][2];
#pragma unroll
        for (int t = 0; t < NTAP; ++t) {
            const int kh = t / 3, kw = t % 3;
            const f16x8* xr = (kh == 0) ? xr0 : (kh == 1) ? xr1 : xr2;
            f16x8 a1 = wl[t * 64 + lane];       // m=1 frag from LDS (per tap)
#pragma unroll
            for (int n = 0; n < 2; ++n) {
                f16x8 bf = xr[off[kw][n]];
                if (t == 0) {
                    acc[0][n] = __builtin_amdgcn_mfma_f32_32x32x16_f16(wreg[0], bf, cb0, 0, 0, 0);
                    acc[1][n] = __builtin_amdgcn_mfma_f32_32x32x16_f16(a1,      bf, cb1, 0, 0, 0);
                } else {
                    acc[0][n] = __builtin_amdgcn_mfma_f32_32x32x16_f16(wreg[t], bf, acc[0][n], 0, 0, 0);
                    acc[1][n] = __builtin_amdgcn_mfma_f32_32x32x16_f16(a1,      bf, acc[1][n], 0, 0, 0);
                }
            }
        }

        // epilogue: min over 64 cout (min3 chain) -> tanh(tanh) -> store
        const int oh = r0 + r;
#pragma unroll
        for (int n = 0; n < 2; ++n) {
            float mn = fminf(acc[0][n][0], acc[1][n][0]);
#pragma unroll
            for (int q = 1; q < 16; ++q)
                mn = min3f(acc[0][n][q], acc[1][n][q], mn);
            mn = fminf(mn, __shfl_xor(mn, 32));
            float t2 = tanh_fast(tanh_fast(mn));
            int px = P + 32 * n + l31;
            if (g2 == 0 && px < OW)
                out[((size_t)b * OH + oh) * OW + px] = t2;
        }

        // write-late: row r+3 -> ring slot (r+3)&3
        if (doStage) SWRITE((r + 3) & 3)

        __syncthreads();   // other 2 resident blocks cover this block's drain
    }
}

extern "C" void kernel_launch(void* const* d_in, const int* in_sizes, int n_in,
                              void* d_out, int out_size, void* d_ws, size_t ws_size,
                              hipStream_t stream) {
    const float* x    = (const float*)d_in[0];
    const float* w    = (const float*)d_in[1];
    const float* bias = (const float*)d_in[2];
    float* out = (float*)d_out;
    _Float16* wpk = (_Float16*)d_ws;   // 9216 fp16 = 18,432 B

    wpack_kernel<<<36, 256, 0, stream>>>(w, wpk);
    conv_mfma_kernel<<<64 * 12, 256, 0, stream>>>(x, (const f16x8*)wpk, bias, out);
}

// Round 11
// 97.138 us; speedup vs baseline: 1.2550x; 1.2550x over previous
//
#include <hip/hip_runtime.h>
#include <math.h>

#define CIN    16
#define COUT   64
#define H      256
#define W      256
#define OH     254
#define OW     254
#define NTAP   9
#define RING   8
#define SROW   264            // f16x8 slots per row region: 2g * 132px
#define NIT    32             // 2-row iterations per block (64 out rows)

typedef _Float16 f16x8  __attribute__((ext_vector_type(8)));
typedef float    f32x16 __attribute__((ext_vector_type(16)));

// Conflict-free px permutation within a row region (verified bank math:
// reads 32-consecutive and writes stride-2 both spread all 8 bank-granules).
#define XP(px) ((px) ^ (((px) >> 3) & 7))

// weight pack: [tap 9][msub 2][lane 64][e 8] fp16; co=(l&31)+32m, cin=8*(l>>5)+e
__global__ void wpack_kernel(const float* __restrict__ w, _Float16* __restrict__ wpk) {
    int idx = blockIdx.x * 256 + threadIdx.x;   // 0..9215
    if (idx >= NTAP * 2 * 64 * 8) return;
    int e = idx & 7, l = (idx >> 3) & 63, m = (idx >> 9) & 1, t = idx >> 10;
    int co  = (l & 31) + 32 * m;
    int cin = 8 * (l >> 5) + e;
    wpk[idx] = (_Float16)w[((co * CIN + cin) * 3 + t / 3) * 3 + (t % 3)];
}

__device__ __forceinline__ float tanh_fast(float v) {
    float e = __expf(2.0f * v);
    return 1.0f - 2.0f * __builtin_amdgcn_rcpf(e + 1.0f);
}
__device__ __forceinline__ float min3f(float a, float b, float c) {
    return fminf(fminf(a, b), c);   // clang fuses to v_min3_f32
}

// 256 thr = 4 waves; block = 128-px column x 64-row strip; 2 blocks/CU.
// Per iteration: 2 output rows, 12 frag reads -> 36 MFMAs, 1 barrier.
__global__ __launch_bounds__(256, 2) void conv_mfma_kernel(
        const float* __restrict__ x, const f16x8* __restrict__ wpk,
        const float* __restrict__ bias, float* __restrict__ out) {
    __shared__ f16x8 xs[RING * SROW];   // 33,792 B: 8-row ring

    const int tid  = threadIdx.x;
    const int lane = tid & 63;

    int bid = blockIdx.x;
    int nb  = (bid & 7) * 64 + (bid >> 3);   // 512 = 8*64 bijective XCD swizzle
    int b   = nb >> 3;                        // image
    int rem = nb & 7;
    const int P0 = (rem & 1) * 128;           // px column base
    const int r0 = (rem >> 1) * 64;           // first out row

    const float* xb = x + (size_t)b * CIN * H * W;

    // ---- weights: global -> 72 VGPRs (loop-invariant) ----
    f16x8 wreg[NTAP][2];
#pragma unroll
    for (int t = 0; t < NTAP; ++t)
#pragma unroll
        for (int m = 0; m < 2; ++m)
            wreg[t][m] = wpk[(t * 2 + m) * 64 + lane];

    const int wave = tid >> 6;
    const int l31  = lane & 31;
    const int g2   = lane >> 5;

    // staging map: thread = [sr 1][sg 1][sp 6]; stages px pair {2sp,2sp+1}
    const int sr = tid >> 7;            // which of the iteration's 2 rows
    const int sg = (tid >> 6) & 1;      // cin half
    const int sp = tid & 63;            // px pair
    const bool hduty = (sp == 63);      // lane also stages halo pair {128,129}

    float2 vm[8];
    float2 vh[8];

#define SLOAD(dRel)                                                             \
    {                                                                           \
        int row_ = r0 + (dRel); if (row_ > 255) row_ = 255;                     \
        const float* p_ = xb + (size_t)row_ * W;                                \
        _Pragma("unroll")                                                       \
        for (int c = 0; c < 8; ++c)                                             \
            vm[c] = *(const float2*)(p_ + (size_t)(8 * sg + c) * (H * W) + P0 + 2 * sp); \
        if (hduty) {                                                            \
            int hp_ = P0 + 128; if (hp_ > 254) hp_ = 254;                       \
            _Pragma("unroll")                                                   \
            for (int c = 0; c < 8; ++c)                                         \
                vh[c] = *(const float2*)(p_ + (size_t)(8 * sg + c) * (H * W) + hp_); \
        }                                                                       \
    }

#define SWRITE(slot)                                                            \
    {                                                                           \
        f16x8 q0, q1;                                                           \
        _Pragma("unroll")                                                       \
        for (int c = 0; c < 8; ++c) { q0[c] = (_Float16)vm[c].x;                \
                                      q1[c] = (_Float16)vm[c].y; }              \
        f16x8* base_ = xs + (slot) * SROW + sg * 132;                           \
        base_[XP(2 * sp)]     = q0;                                             \
        base_[XP(2 * sp + 1)] = q1;                                             \
        if (hduty) {                                                            \
            f16x8 h0, h1;                                                       \
            _Pragma("unroll")                                                   \
            for (int c = 0; c < 8; ++c) { h0[c] = (_Float16)vh[c].x;            \
                                          h1[c] = (_Float16)vh[c].y; }          \
            base_[XP(128)] = h0;                                                \
            base_[XP(129)] = h1;                                                \
        }                                                                       \
    }

    // ---- prologue: input rows d=0..5 -> slots 0..5 ----
#pragma unroll
    for (int j = 0; j < 3; ++j) {
        SLOAD(2 * j + sr)
        SWRITE(2 * j + sr)
    }

    // fragment read offsets (loop-invariant): locpx = 32*wave + l31 + kw <= 129
    int roff[3];
#pragma unroll
    for (int kw = 0; kw < 3; ++kw)
        roff[kw] = g2 * 132 + XP(32 * wave + l31 + kw);

    // bias as MFMA C-fragment: col=l31(px), row=(r&3)+8*(r>>2)+4*g2+32m (co)
    f32x16 cbias[2];
#pragma unroll
    for (int m = 0; m < 2; ++m)
#pragma unroll
        for (int r = 0; r < 16; ++r)
            cbias[m][r] = bias[(r & 3) + 8 * (r >> 2) + 4 * g2 + 32 * m];

    __syncthreads();

#pragma unroll 1
    for (int i = 0; i < NIT; ++i) {
        const bool pf = (i < 30);
        // issue-early: loads for input rows d = 2i+6, 2i+7
        if (pf) SLOAD(2 * i + 6 + sr)

        f32x16 acc[2][2];   // [ro][m]
        // dd-major: read 3 kw-frags of input row 2i+dd, feed all (ro,kh) with ro+kh==dd
#pragma unroll
        for (int dd = 0; dd < 4; ++dd) {
            const f16x8* xr = xs + ((2 * i + dd) & 7) * SROW;
            f16x8 f0 = xr[roff[0]];
            f16x8 f1 = xr[roff[1]];
            f16x8 f2 = xr[roff[2]];
#pragma unroll
            for (int ro = 0; ro < 2; ++ro) {
                const int kh = dd - ro;
                if (kh < 0 || kh > 2) continue;
#pragma unroll
                for (int m = 0; m < 2; ++m) {
                    if (kh == 0)
                        acc[ro][m] = __builtin_amdgcn_mfma_f32_32x32x16_f16(wreg[0][m], f0, cbias[m], 0, 0, 0);
                    else
                        acc[ro][m] = __builtin_amdgcn_mfma_f32_32x32x16_f16(wreg[kh * 3][m], f0, acc[ro][m], 0, 0, 0);
                    acc[ro][m] = __builtin_amdgcn_mfma_f32_32x32x16_f16(wreg[kh * 3 + 1][m], f1, acc[ro][m], 0, 0, 0);
                    acc[ro][m] = __builtin_amdgcn_mfma_f32_32x32x16_f16(wreg[kh * 3 + 2][m], f2, acc[ro][m], 0, 0, 0);
                }
            }
        }

        // barrier: all waves done reading rows 2i..2i+3 -> safe to overwrite d=2i-2
        __syncthreads();
        if (pf) SWRITE((2 * i + 6 + sr) & 7)

        // epilogue: per out-row min over 64 cout -> tanh(tanh) -> store
#pragma unroll
        for (int ro = 0; ro < 2; ++ro) {
            const int oh = r0 + 2 * i + ro;
            float mn = fminf(acc[ro][0][0], acc[ro][1][0]);
#pragma unroll
            for (int q = 1; q < 16; ++q)
                mn = min3f(acc[ro][0][q], acc[ro][1][q], mn);
            mn = fminf(mn, __shfl_xor(mn, 32));
            float t2 = tanh_fast(tanh_fast(mn));
            const int px = P0 + 32 * wave + l31;
            if (g2 == 0 && px < OW && oh < OH)
                out[((size_t)b * OH + oh) * OW + px] = t2;
        }
    }
}

extern "C" void kernel_launch(void* const* d_in, const int* in_sizes, int n_in,
                              void* d_out, int out_size, void* d_ws, size_t ws_size,
                              hipStream_t stream) {
    const float* x    = (const float*)d_in[0];
    const float* w    = (const float*)d_in[1];
    const float* bias = (const float*)d_in[2];
    float* out = (float*)d_out;
    _Float16* wpk = (_Float16*)d_ws;   // 9216 fp16 = 18,432 B

    wpack_kernel<<<36, 256, 0, stream>>>(w, wpk);
    conv_mfma_kernel<<<512, 256, 0, stream>>>(x, (const f16x8*)wpk, bias, out);
}

// Round 12
// 91.266 us; speedup vs baseline: 1.3358x; 1.0643x over previous
//
#include <hip/hip_runtime.h>
#include <math.h>

#define CIN   16
#define COUT  64
#define H     256
#define W     256
#define OH    254
#define OW    254
#define NTAP  9
#define TROWS 16          // output rows per tile
#define IROWS 18          // input rows staged
#define SROW  264         // f16x8 slots per row region: 2 g * 132 px
#define HWSZ  (H * W)

typedef _Float16 f16x8  __attribute__((ext_vector_type(8)));
typedef float    f32x16 __attribute__((ext_vector_type(16)));

// weight pack: [tap 9][msub 2][lane 64][e 8] fp16; co=(l&31)+32m, cin=8*(l>>5)+e
__global__ void wpack_kernel(const float* __restrict__ w, _Float16* __restrict__ wpk) {
    int idx = blockIdx.x * 256 + threadIdx.x;   // 0..9215
    if (idx >= NTAP * 2 * 64 * 8) return;
    int e = idx & 7, l = (idx >> 3) & 63, m = (idx >> 9) & 1, t = idx >> 10;
    int co  = (l & 31) + 32 * m;
    int cin = 8 * (l >> 5) + e;
    wpk[idx] = (_Float16)w[((co * CIN + cin) * 3 + t / 3) * 3 + (t % 3)];
}

__device__ __forceinline__ float tanh_fast(float v) {
    float e = __expf(2.0f * v);
    return 1.0f - 2.0f * __builtin_amdgcn_rcpf(e + 1.0f);
}
__device__ __forceinline__ float min3f(float a, float b, float c) {
    return fminf(fminf(a, b), c);   // clang fuses to v_min3_f32
}

// 256 thr = 4 waves; block = 16-row x 128-px tile; 2 blocks/CU (LDS-capped).
// Phase 1: bulk-stage 18 input rows (depth-2 pipelined, sched_barrier-pinned).
// Phase 2: pure-LDS compute, 8 pair-steps, no barriers, no global reads.
__global__ __launch_bounds__(256, 2) void conv_mfma_kernel(
        const float* __restrict__ x, const f16x8* __restrict__ wpk,
        const float* __restrict__ bias, float* __restrict__ out) {
    __shared__ f16x8 xs[IROWS * SROW];   // 76,032 B

    const int tid  = threadIdx.x;
    const int lane = tid & 63;

    int bid = blockIdx.x;
    int nb  = (bid & 7) * 256 + (bid >> 3);   // 2048 = 8*256 bijective XCD swizzle
    const int b    = nb >> 5;                 // image
    const int rem  = nb & 31;
    const int v    = rem >> 1;                // vertical tile 0..15
    const int col  = rem & 1;                 // px column 0..1
    const int r0   = v * TROWS;
    const int base = col ? 124 : 0;           // staged global px origin
    const int P0   = col * 128;               // output px origin

    const float* xb = x + (size_t)b * CIN * HWSZ;

    // ---- weights: global -> 72 VGPRs (loop-invariant) ----
    f16x8 wreg[NTAP][2];
#pragma unroll
    for (int t = 0; t < NTAP; ++t)
#pragma unroll
        for (int m = 0; m < 2; ++m)
            wreg[t][m] = wpk[(t * 2 + m) * 64 + lane];

    // ================= PHASE 1: bulk staging =================
    // main units: 2304 = 18 rows * 2 g * 64 px-pairs (pure-shift decode),
    // 9 rounds of 256; halo units: 72 = 18 rows * 2 g * 2 pairs (px 128..131).
    float2 vA[8], vB[8];

#define LOADU(k, vv)                                                            \
    {                                                                           \
        const int u_ = tid + 256 * (k);                                         \
        const int row_ = u_ >> 7;                                               \
        const int gq_  = (u_ >> 6) & 1;                                         \
        const int p_   = u_ & 63;                                               \
        int grow_ = r0 + row_; if (grow_ > 255) grow_ = 255;                    \
        const float* gp_ = xb + (size_t)gq_ * 8 * HWSZ + (size_t)grow_ * W      \
                              + base + 2 * p_;                                  \
        _Pragma("unroll")                                                       \
        for (int c = 0; c < 8; ++c) vv[c] = *(const float2*)(gp_ + (size_t)c * HWSZ); \
    }                                                                           \
    __builtin_amdgcn_sched_barrier(0);

#define WRITEU(k, vv)                                                           \
    {                                                                           \
        const int u_ = tid + 256 * (k);                                         \
        const int row_ = u_ >> 7;                                               \
        const int gq_  = (u_ >> 6) & 1;                                         \
        const int p_   = u_ & 63;                                               \
        f16x8 q0_, q1_;                                                         \
        _Pragma("unroll")                                                       \
        for (int c = 0; c < 8; ++c) { q0_[c] = (_Float16)vv[c].x;               \
                                      q1_[c] = (_Float16)vv[c].y; }             \
        const int sl_ = row_ * SROW + gq_ * 132 + 2 * p_;                       \
        xs[sl_]     = q0_;                                                      \
        xs[sl_ + 1] = q1_;                                                      \
    }

#define LOADH(vv)                                                               \
    if (tid < 72) {                                                             \
        const int row_ = tid >> 2;                                              \
        const int gq_  = (tid >> 1) & 1;                                        \
        const int pp_  = tid & 1;                                               \
        int grow_ = r0 + row_; if (grow_ > 255) grow_ = 255;                    \
        const float* gp_ = xb + (size_t)gq_ * 8 * HWSZ + (size_t)grow_ * W      \
                              + base + 128 + 2 * pp_;                           \
        _Pragma("unroll")                                                       \
        for (int c = 0; c < 8; ++c) vv[c] = *(const float2*)(gp_ + (size_t)c * HWSZ); \
    }                                                                           \
    __builtin_amdgcn_sched_barrier(0);

#define WRITEH(vv)                                                              \
    if (tid < 72) {                                                             \
        const int row_ = tid >> 2;                                              \
        const int gq_  = (tid >> 1) & 1;                                        \
        const int pp_  = tid & 1;                                               \
        f16x8 q0_, q1_;                                                         \
        _Pragma("unroll")                                                       \
        for (int c = 0; c < 8; ++c) { q0_[c] = (_Float16)vv[c].x;               \
                                      q1_[c] = (_Float16)vv[c].y; }             \
        const int sl_ = row_ * SROW + gq_ * 132 + 128 + 2 * pp_;                \
        xs[sl_]     = q0_;                                                      \
        xs[sl_ + 1] = q1_;                                                      \
    }

    LOADU(0, vA)
    LOADU(1, vB)
    WRITEU(0, vA)
    LOADU(2, vA)
    WRITEU(1, vB)
    LOADU(3, vB)
    WRITEU(2, vA)
    LOADU(4, vA)
    WRITEU(3, vB)
    LOADU(5, vB)
    WRITEU(4, vA)
    LOADU(6, vA)
    WRITEU(5, vB)
    LOADU(7, vB)
    WRITEU(6, vA)
    LOADU(8, vA)
    WRITEU(7, vB)
    LOADH(vB)
    WRITEU(8, vA)
    WRITEH(vB)

    // ---- loop-invariant compute setup (overlaps staging tail) ----
    const int wave = tid >> 6;
    const int l31  = lane & 31;
    const int g2   = lane >> 5;

    int roff[3];
#pragma unroll
    for (int kw = 0; kw < 3; ++kw) {
        int lp = (col ? 4 : 0) + 32 * wave + l31 + kw;
        if (lp > 131) lp = 131;               // only feeds masked outputs
        roff[kw] = g2 * 132 + lp;
    }

    // bias as MFMA C-fragment: col=l31(px), row=(r&3)+8*(r>>2)+4*g2+32m (co)
    f32x16 cbias[2];
#pragma unroll
    for (int m = 0; m < 2; ++m)
#pragma unroll
        for (int r = 0; r < 16; ++r)
            cbias[m][r] = bias[(r & 3) + 8 * (r >> 2) + 4 * g2 + 32 * m];

    __syncthreads();

    // ================= PHASE 2: pure-LDS compute =================
#pragma unroll 1
    for (int i = 0; i < TROWS / 2; ++i) {
        f32x16 acc[2][2];   // [ro][m]
#pragma unroll
        for (int dd = 0; dd < 4; ++dd) {
            const f16x8* xr = xs + (2 * i + dd) * SROW;
            f16x8 f0 = xr[roff[0]];
            f16x8 f1 = xr[roff[1]];
            f16x8 f2 = xr[roff[2]];
#pragma unroll
            for (int ro = 0; ro < 2; ++ro) {
                const int kh = dd - ro;
                if (kh < 0 || kh > 2) continue;
#pragma unroll
                for (int m = 0; m < 2; ++m) {
                    if (kh == 0)
                        acc[ro][m] = __builtin_amdgcn_mfma_f32_32x32x16_f16(wreg[0][m], f0, cbias[m], 0, 0, 0);
                    else
                        acc[ro][m] = __builtin_amdgcn_mfma_f32_32x32x16_f16(wreg[kh * 3][m], f0, acc[ro][m], 0, 0, 0);
                    acc[ro][m] = __builtin_amdgcn_mfma_f32_32x32x16_f16(wreg[kh * 3 + 1][m], f1, acc[ro][m], 0, 0, 0);
                    acc[ro][m] = __builtin_amdgcn_mfma_f32_32x32x16_f16(wreg[kh * 3 + 2][m], f2, acc[ro][m], 0, 0, 0);
                }
            }
        }

        // epilogue: per out-row min over 64 cout -> tanh(tanh) -> store
#pragma unroll
        for (int ro = 0; ro < 2; ++ro) {
            const int oh = r0 + 2 * i + ro;
            float mn = fminf(acc[ro][0][0], acc[ro][1][0]);
#pragma unroll
            for (int q = 1; q < 16; ++q)
                mn = min3f(acc[ro][0][q], acc[ro][1][q], mn);
            mn = fminf(mn, __shfl_xor(mn, 32));
            float t2 = tanh_fast(tanh_fast(mn));
            const int px = P0 + 32 * wave + l31;
            if (g2 == 0 && px < OW && oh < OH)
                out[((size_t)b * OH + oh) * OW + px] = t2;
        }
    }
}

extern "C" void kernel_launch(void* const* d_in, const int* in_sizes, int n_in,
                              void* d_out, int out_size, void* d_ws, size_t ws_size,
                              hipStream_t stream) {
    const float* x    = (const float*)d_in[0];
    const float* w    = (const float*)d_in[1];
    const float* bias = (const float*)d_in[2];
    float* out = (float*)d_out;
    _Float16* wpk = (_Float16*)d_ws;   // 9216 fp16 = 18,432 B

    wpack_kernel<<<36, 256, 0, stream>>>(w, wpk);
    conv_mfma_kernel<<<2048, 256, 0, stream>>>(x, (const f16x8*)wpk, bias, out);
}